// Round 12
// baseline (771.111 us; speedup 1.0000x reference)
//
#include <hip/hip_runtime.h>
#include <stdint.h>

#define S_LEN 2048
#define DMODEL 1024
#define NHEAD 16
#define DKH 64
#define NROW 4096  // B*S

using short8  = __attribute__((ext_vector_type(8))) short;
using short4v = __attribute__((ext_vector_type(4))) short;
using float4v = __attribute__((ext_vector_type(4))) float;

__device__ __forceinline__ short f2bf(float f) {
    union { float f; unsigned u; } v; v.f = f;
    unsigned r = (v.u + 0x7fffu + ((v.u >> 16) & 1u)) >> 16;
    return (short)r;
}

__device__ __forceinline__ float bf2f(short b) {
    union { unsigned u; float f; } c;
    c.u = ((unsigned)(unsigned short)b) << 16;
    return c.f;
}

__device__ __forceinline__ float4v mfma16(short8 a, short8 b, float4v c) {
    return __builtin_amdgcn_mfma_f32_16x16x32_bf16(a, b, c, 0, 0, 0);
}

// async global->LDS, 16B per lane. LDS dest = wave-uniform base + lane*16.
__device__ __forceinline__ void gload16(const short* g, short* l) {
    __builtin_amdgcn_global_load_lds(
        (const __attribute__((address_space(1))) void*)g,
        (__attribute__((address_space(3))) void*)l, 16, 0, 0);
}

// ---------------------------------------------------------------- convert
__global__ __launch_bounds__(256) void convert_kernel(
    const float* __restrict__ q, const float* __restrict__ k, const float* __restrict__ v,
    const float* __restrict__ wq, const float* __restrict__ wk, const float* __restrict__ wv,
    const float* __restrict__ wo,
    short* __restrict__ oq, short* __restrict__ ok_, short* __restrict__ ov,
    short* __restrict__ owq, short* __restrict__ owk, short* __restrict__ owv,
    short* __restrict__ owo)
{
    const size_t A = (size_t)NROW * DMODEL;      // 4194304
    const size_t W = (size_t)DMODEL * DMODEL;    // 1048576
    size_t i = ((size_t)blockIdx.x * 256 + threadIdx.x) * 4;
    const float* src; short* dst; size_t off;
    if (i < A)            { src = q;  dst = oq;  off = i; }
    else if (i < 2 * A)   { src = k;  dst = ok_; off = i - A; }
    else if (i < 3 * A)   { src = v;  dst = ov;  off = i - 2 * A; }
    else {
        size_t j = i - 3 * A; int wsel = (int)(j / W); off = j % W;
        src = (wsel == 0) ? wq : (wsel == 1) ? wk : (wsel == 2) ? wv : wo;
        dst = (wsel == 0) ? owq : (wsel == 1) ? owk : (wsel == 2) ? owv : owo;
    }
    float4v x = *(const float4v*)(src + off);
    short4v o;
    o[0] = f2bf(x[0]); o[1] = f2bf(x[1]); o[2] = f2bf(x[2]); o[3] = f2bf(x[3]);
    *(short4v*)(dst + off) = o;
}

// ---------------------------------------------------------------- fused QKV GEMM (m97 structure)
__global__ __launch_bounds__(256) void gemm_qkv(
    const short* __restrict__ Xq, const short* __restrict__ Xk, const short* __restrict__ Xv,
    const short* __restrict__ Wq, const short* __restrict__ Wk, const short* __restrict__ Wv,
    const float* __restrict__ bq, const float* __restrict__ bk, const float* __restrict__ bv,
    short* __restrict__ Qo, short* __restrict__ Ko, short* __restrict__ Vt)
{
    int zy = blockIdx.y;
    int z = zy >> 3;                 // 0=Q 1=K 2=V
    int n0 = (zy & 7) * 128;
    const short* X = (z == 0) ? Xq : (z == 1) ? Xk : Xv;
    const short* W = (z == 0) ? Wq : (z == 1) ? Wk : Wv;
    const float* bias = (z == 0) ? bq : (z == 1) ? bk : bv;
    int m0 = blockIdx.x * 128;

    __shared__ __align__(16) short As[128 * 32];
    __shared__ __align__(16) short Bs[128 * 32];

    int tid = threadIdx.x, lane = tid & 63, w = tid >> 6;
    int row_in = lane & 15, grp = lane >> 4;
    int wm = (w & 1) * 64, wn = (w >> 1) * 64;

    float4v acc[4][4];
#pragma unroll
    for (int m = 0; m < 4; m++)
#pragma unroll
        for (int n = 0; n < 4; n++) acc[m][n] = (float4v){0.f, 0.f, 0.f, 0.f};

    for (int k0 = 0; k0 < DMODEL; k0 += 32) {
#pragma unroll
        for (int j = 0; j < 2; j++) {
            int chunk = j * 256 + tid;
            int r = chunk >> 2, c = (chunk & 3) * 8;
            gload16(X + (size_t)(m0 + r) * DMODEL + k0 + c,
                    As + (size_t)(j * 256 + w * 64) * 8);
            gload16(W + (size_t)(n0 + r) * DMODEL + k0 + c,
                    Bs + (size_t)(j * 256 + w * 64) * 8);
        }
        __syncthreads();

        short8 af[4], bf[4];
#pragma unroll
        for (int m = 0; m < 4; m++)
            af[m] = *(const short8*)&As[(wm + m * 16 + row_in) * 32 + grp * 8];
#pragma unroll
        for (int n = 0; n < 4; n++)
            bf[n] = *(const short8*)&Bs[(wn + n * 16 + row_in) * 32 + grp * 8];
#pragma unroll
        for (int m = 0; m < 4; m++)
#pragma unroll
            for (int n = 0; n < 4; n++)
                acc[m][n] = mfma16(af[m], bf[n], acc[m][n]);
        __syncthreads();
    }

#pragma unroll
    for (int m = 0; m < 4; m++) {
#pragma unroll
        for (int n = 0; n < 4; n++) {
            int col = n0 + wn + n * 16 + row_in;
            int h = col >> 6, dk = col & 63;
            float bval = bias[col];
            if (z < 2) {
                short* dst = (z == 0) ? Qo : Ko;
#pragma unroll
                for (int r = 0; r < 4; r++) {
                    int rowg = m0 + wm + m * 16 + grp * 4 + r;
                    int bb = rowg >> 11, s = rowg & 2047;
                    dst[(((size_t)(bb * NHEAD + h)) * S_LEN + s) * DKH + dk] =
                        f2bf(acc[m][n][r] + bval);
                }
            } else {
                int rowg0 = m0 + wm + m * 16 + grp * 4;
                int bb = rowg0 >> 11, s0 = rowg0 & 2047;
                short4v pk;
#pragma unroll
                for (int r = 0; r < 4; r++) pk[r] = f2bf(acc[m][n][r] + bval);
                *(short4v*)(Vt + ((size_t)(bb * NHEAD + h) * DKH + dk) * S_LEN + s0) = pk;
            }
        }
    }
}

// ---------------------------------------------------------------- output projection
__global__ __launch_bounds__(256) void gemm_out(
    const short* __restrict__ X, const short* __restrict__ W,
    const float* __restrict__ bias, float* __restrict__ out)
{
    int m0 = blockIdx.x * 128, n0 = blockIdx.y * 128;

    __shared__ __align__(16) short As[128 * 32];
    __shared__ __align__(16) short Bs[128 * 32];

    int tid = threadIdx.x, lane = tid & 63, w = tid >> 6;
    int row_in = lane & 15, grp = lane >> 4;
    int wm = (w & 1) * 64, wn = (w >> 1) * 64;

    float4v acc[4][4];
#pragma unroll
    for (int m = 0; m < 4; m++)
#pragma unroll
        for (int n = 0; n < 4; n++) acc[m][n] = (float4v){0.f, 0.f, 0.f, 0.f};

    for (int k0 = 0; k0 < DMODEL; k0 += 32) {
#pragma unroll
        for (int j = 0; j < 2; j++) {
            int chunk = j * 256 + tid;
            int r = chunk >> 2, c = (chunk & 3) * 8;
            gload16(X + (size_t)(m0 + r) * DMODEL + k0 + c,
                    As + (size_t)(j * 256 + w * 64) * 8);
            gload16(W + (size_t)(n0 + r) * DMODEL + k0 + c,
                    Bs + (size_t)(j * 256 + w * 64) * 8);
        }
        __syncthreads();

        short8 af[4], bf[4];
#pragma unroll
        for (int m = 0; m < 4; m++)
            af[m] = *(const short8*)&As[(wm + m * 16 + row_in) * 32 + grp * 8];
#pragma unroll
        for (int n = 0; n < 4; n++)
            bf[n] = *(const short8*)&Bs[(wn + n * 16 + row_in) * 32 + grp * 8];
#pragma unroll
        for (int m = 0; m < 4; m++)
#pragma unroll
            for (int n = 0; n < 4; n++)
                acc[m][n] = mfma16(af[m], bf[n], acc[m][n]);
        __syncthreads();
    }

#pragma unroll
    for (int m = 0; m < 4; m++)
#pragma unroll
        for (int n = 0; n < 4; n++) {
            int col = n0 + wn + n * 16 + row_in;
            float bval = bias[col];
#pragma unroll
            for (int r = 0; r < 4; r++) {
                int rowg = m0 + wm + m * 16 + grp * 4 + r;
                out[(size_t)rowg * DMODEL + col] = acc[m][n][r] + bval;
            }
        }
}

// ---------------------------------------------------------------- attention kernel A (single pass)
// Per (bh, q-strip of 64 rows): one pass over causal K/V tiles.
// QK^T + exp once, row-sum l, UNNORMALIZED PV accumulate (scale commutes).
// Epilogue: rinv = 1/l -> global rinvg (for writer kernel) + normalized Xatt.
// NO attention-matrix write here. Critical path: 32 tile-iterations (was 64).
__global__ __launch_bounds__(256) void attn_kernel(
    const short* __restrict__ Q, const short* __restrict__ K, const short* __restrict__ Vt,
    float* __restrict__ rinvg, short* __restrict__ Xatt)
{
    int bh = blockIdx.x;
    int q0 = (int)(gridDim.y - 1 - blockIdx.y) * 64;   // heavy causal blocks first
    int tid = threadIdx.x, lane = tid & 63, w = tid >> 6;
    int row_in = lane & 15, grp = lane >> 4;
    int qbase = q0 + w * 16;

    const short* Qh = Q + (size_t)bh * S_LEN * DKH;
    const short* Kh = K + (size_t)bh * S_LEN * DKH;
    const short* Vh = Vt + (size_t)bh * DKH * S_LEN;

    __shared__ __align__(16) short Ks[64 * 72];      // 9216 B
    __shared__ __align__(16) short Vs[64 * 72];      // 9216 B
    __shared__ __align__(16) short Plds[4][16 * 72]; // 9216 B (wave-private slices)

    short8 qf0 = *(const short8*)(Qh + (size_t)(qbase + row_in) * DKH + grp * 8);
    short8 qf1 = *(const short8*)(Qh + (size_t)(qbase + row_in) * DKH + 32 + grp * 8);

    const float SC = 0.125f * 1.44269504f;  // fold score scale into exp2
    float l[4] = {0.f, 0.f, 0.f, 0.f};
    float4v o[4];
#pragma unroll
    for (int v = 0; v < 4; v++) o[v] = (float4v){0.f, 0.f, 0.f, 0.f};
    int Tmax = q0 / 64 + 1;  // causal tiles for this block

    for (int t = 0; t < Tmax; t++) {
        int kv0 = t * 64;
        // cooperative K+V tile stage into padded LDS
        {
            const short* srcK = Kh + (size_t)kv0 * DKH;
#pragma unroll
            for (int j = 0; j < 2; j++) {
                int ch = j * 256 + tid;
                int r = ch >> 3, c = (ch & 7) * 8;
                short8 kv = *(const short8*)(srcK + ch * 8);
                *(short8*)&Ks[r * 72 + c] = kv;
                short8 vv = *(const short8*)(Vh + (size_t)r * S_LEN + kv0 + c);
                *(short8*)&Vs[r * 72 + c] = vv;
            }
        }
        __syncthreads();
        // QK^T + exp -> l and Plds (unnormalized bf16 e)
#pragma unroll
        for (int u = 0; u < 4; u++) {
            short8 b0 = *(const short8*)&Ks[(u * 16 + row_in) * 72 + grp * 8];
            short8 b1 = *(const short8*)&Ks[(u * 16 + row_in) * 72 + 32 + grp * 8];
            float4v a = (float4v){0.f, 0.f, 0.f, 0.f};
            a = mfma16(qf0, b0, a);
            a = mfma16(qf1, b1, a);
            int colg = kv0 + u * 16 + row_in;
#pragma unroll
            for (int r = 0; r < 4; r++) {
                int rowg = qbase + grp * 4 + r;
                float e = (colg > rowg) ? 0.0f : exp2f(a[r] * SC);
                l[r] += e;
                Plds[w][(grp * 4 + r) * 72 + u * 16 + row_in] = f2bf(e);
            }
        }
        asm volatile("s_waitcnt lgkmcnt(0)" ::: "memory");
        // PV with unnormalized P (wave-private Plds slice)
        short8 pa0 = *(const short8*)&Plds[w][row_in * 72 + grp * 8];
        short8 pa1 = *(const short8*)&Plds[w][row_in * 72 + 32 + grp * 8];
#pragma unroll
        for (int v = 0; v < 4; v++) {
            short8 b0 = *(const short8*)&Vs[(v * 16 + row_in) * 72 + grp * 8];
            short8 b1 = *(const short8*)&Vs[(v * 16 + row_in) * 72 + 32 + grp * 8];
            o[v] = mfma16(pa0, b0, o[v]);
            o[v] = mfma16(pa1, b1, o[v]);
        }
        __syncthreads();
    }

    // cross-lane row sums (16 column-lanes per row group) -> rinv
    float rinv[4];
#pragma unroll
    for (int r = 0; r < 4; r++) {
        float s = l[r];
        s += __shfl_xor(s, 1, 64);
        s += __shfl_xor(s, 2, 64);
        s += __shfl_xor(s, 4, 64);
        s += __shfl_xor(s, 8, 64);
        rinv[r] = 1.0f / s;
    }
    // publish rinv for the writer kernel
    if (row_in == 0) {
#pragma unroll
        for (int r = 0; r < 4; r++)
            rinvg[(size_t)bh * S_LEN + qbase + grp * 4 + r] = rinv[r];
    }

    // epilogue: normalized O -> Xatt (bf16, [B,S,D] with col = h*64+dk)
    int b = bh >> 4, h = bh & 15;
#pragma unroll
    for (int v = 0; v < 4; v++) {
#pragma unroll
        for (int r = 0; r < 4; r++) {
            int s = qbase + grp * 4 + r;
            int col = h * 64 + v * 16 + row_in;
            Xatt[(size_t)(b * S_LEN + s) * DMODEL + col] = f2bf(o[v][r] * rinv[r]);
        }
    }
}

// ---------------------------------------------------------------- attention kernel B (balanced writer, COALESCED)
// Block (bh, t) owns kv-column stripe [64t, 64t+64) for ALL 2048 q rows.
// K staged once, K fragments hoisted to registers (loop-invariant).
// Every block: exactly 32 store-iterations (t zero-fill strips + 32-t computed
// strips) -> perfectly balanced grid, no barriers in the hot loop.
// FIX vs round 5: stores go through the baseline's proven Plds-repack path
// (wave-private LDS, lgkmcnt wait, 16B/lane float4 -> 256B contiguous
// segments per row) with rinv folded in BEFORE f2bf -> attention values are
// bitwise identical to the 731-baseline.
__global__ __launch_bounds__(256) void attn_write_kernel(
    const short* __restrict__ Q, const short* __restrict__ K,
    const float* __restrict__ rinvg, float* __restrict__ Attn)
{
    int bh = blockIdx.x;
    int t  = blockIdx.y;
    int kv0 = t * 64;
    int tid = threadIdx.x, lane = tid & 63, w = tid >> 6;
    int row_in = lane & 15, grp = lane >> 4;

    const short* Qh = Q + (size_t)bh * S_LEN * DKH;
    const short* Kh = K + (size_t)bh * S_LEN * DKH;
    const float* rh = rinvg + (size_t)bh * S_LEN;
    float* Ah = Attn + (size_t)bh * S_LEN * S_LEN;

    __shared__ __align__(16) short Ks[64 * 72];
    __shared__ __align__(16) short Plds[4][16 * 72];  // wave-private slices
    {
        const short* srcK = Kh + (size_t)kv0 * DKH;
#pragma unroll
        for (int j = 0; j < 2; j++) {
            int ch = j * 256 + tid;
            int r = ch >> 3, c = (ch & 7) * 8;
            *(short8*)&Ks[r * 72 + c] = *(const short8*)(srcK + ch * 8);
        }
    }
    __syncthreads();

    // hoist K fragments: loop-invariant across all q-strips (32 VGPRs)
    short8 kb0[4], kb1[4];
#pragma unroll
    for (int u = 0; u < 4; u++) {
        kb0[u] = *(const short8*)&Ks[(u * 16 + row_in) * 72 + grp * 8];
        kb1[u] = *(const short8*)&Ks[(u * 16 + row_in) * 72 + 32 + grp * 8];
    }

    // zero-fill strips s < t (rows strictly above the causal range)
    float4v zz = (float4v){0.f, 0.f, 0.f, 0.f};
    for (int s = 0; s < t; s++) {
        float* base = Ah + (size_t)(s * 64) * S_LEN + kv0;
#pragma unroll
        for (int kk = 0; kk < 4; kk++) {
            int idx = kk * 256 + tid;
            int r = idx >> 4, c = (idx & 15) * 4;
            *(float4v*)(base + (size_t)r * S_LEN + c) = zz;
        }
    }

    const float SC = 0.125f * 1.44269504f;
    // software-pipelined Q-fragment loads (hide L2 latency under compute)
    int qb = t * 64 + w * 16;
    short8 qf0 = *(const short8*)(Qh + (size_t)(qb + row_in) * DKH + grp * 8);
    short8 qf1 = *(const short8*)(Qh + (size_t)(qb + row_in) * DKH + 32 + grp * 8);

    for (int s = t; s < 32; s++) {
        int qbase = s * 64 + w * 16;
        // prefetch next strip's Q fragments
        short8 nq0 = qf0, nq1 = qf1;
        if (s + 1 < 32) {
            int nqb = (s + 1) * 64 + w * 16;
            nq0 = *(const short8*)(Qh + (size_t)(nqb + row_in) * DKH + grp * 8);
            nq1 = *(const short8*)(Qh + (size_t)(nqb + row_in) * DKH + 32 + grp * 8);
        }
        float rv[4];
#pragma unroll
        for (int r = 0; r < 4; r++) rv[r] = rh[qbase + grp * 4 + r];
        // QK^T + exp -> normalized bf16 P into wave-private Plds
#pragma unroll
        for (int u = 0; u < 4; u++) {
            float4v a = (float4v){0.f, 0.f, 0.f, 0.f};
            a = mfma16(qf0, kb0[u], a);
            a = mfma16(qf1, kb1[u], a);
            int colg = kv0 + u * 16 + row_in;
#pragma unroll
            for (int r = 0; r < 4; r++) {
                int rowg = qbase + grp * 4 + r;
                float p = (colg > rowg) ? 0.0f : exp2f(a[r] * SC) * rv[r];
                Plds[w][(grp * 4 + r) * 72 + u * 16 + row_in] = f2bf(p);
            }
        }
        asm volatile("s_waitcnt lgkmcnt(0)" ::: "memory");
        // coalesced f32 store: 16B/lane, 256B contiguous per row (baseline path)
#pragma unroll
        for (int rr = 0; rr < 4; rr++) {
            int rloc = rr * 4 + grp;
            short4v pb = *(const short4v*)&Plds[w][rloc * 72 + row_in * 4];
            float4v pf;
#pragma unroll
            for (int i = 0; i < 4; i++) pf[i] = bf2f(pb[i]);
            *(float4v*)(Ah + (size_t)(s * 64 + w * 16 + rloc) * S_LEN + kv0 + row_in * 4) = pf;
        }
        asm volatile("s_waitcnt lgkmcnt(0)" ::: "memory");  // Plds WAR guard
        qf0 = nq0; qf1 = nq1;
    }
}

// ---------------------------------------------------------------- launch
extern "C" void kernel_launch(void* const* d_in, const int* in_sizes, int n_in,
                              void* d_out, int out_size, void* d_ws, size_t ws_size,
                              hipStream_t stream) {
    const float* q  = (const float*)d_in[0];
    const float* k  = (const float*)d_in[1];
    const float* v  = (const float*)d_in[2];
    const float* Wq = (const float*)d_in[4];
    const float* bq = (const float*)d_in[5];
    const float* Wk = (const float*)d_in[6];
    const float* bk = (const float*)d_in[7];
    const float* Wv = (const float*)d_in[8];
    const float* bv = (const float*)d_in[9];
    const float* Wo = (const float*)d_in[10];
    const float* bo = (const float*)d_in[11];

    float* out_x    = (float*)d_out;
    float* out_attn = out_x + (size_t)NROW * DMODEL;

    char* ws = (char*)d_ws;
    size_t off = 0;
    auto carve = [&](size_t bytes) -> char* {
        char* p = ws + off;
        off += (bytes + 255) & ~(size_t)255;
        return p;
    };
    const size_t XB = (size_t)NROW * DMODEL * sizeof(short);
    const size_t WB = (size_t)DMODEL * DMODEL * sizeof(short);
    short* Xq  = (short*)carve(XB);
    short* Xk  = (short*)carve(XB);
    short* Xv  = (short*)carve(XB);
    short* Wqb = (short*)carve(WB);
    short* Wkb = (short*)carve(WB);
    short* Wvb = (short*)carve(WB);
    short* Wob = (short*)carve(WB);
    short* Qb  = (short*)carve(XB);   // [BH, S, DK]
    short* Kb  = (short*)carve(XB);   // [BH, S, DK]
    short* Vtb = (short*)carve(XB);   // [BH, DK, S]
    short* Xat = (short*)carve(XB);   // attention output pre-Wo
    float* Rin = (float*)carve((size_t)2 * NHEAD * S_LEN * sizeof(float));  // rinv

    convert_kernel<<<dim3(16384), dim3(256), 0, stream>>>(
        q, k, v, Wq, Wk, Wv, Wo, Xq, Xk, Xv, Wqb, Wkb, Wvb, Wob);

    gemm_qkv<<<dim3(NROW / 128, 24), dim3(256), 0, stream>>>(
        Xq, Xk, Xv, Wqb, Wkb, Wvb, bq, bk, bv, Qb, Kb, Vtb);

    attn_kernel<<<dim3(32, S_LEN / 64), dim3(256), 0, stream>>>(
        Qb, Kb, Vtb, Rin, Xat);

    gemm_out<<<dim3(NROW / 128, DMODEL / 128), dim3(256), 0, stream>>>(
        Xat, Wob, bo, out_x);

    attn_write_kernel<<<dim3(32, 32), dim3(256), 0, stream>>>(
        Qb, Kb, Rin, out_attn);
}

// Round 13
// 730.851 us; speedup vs baseline: 1.0551x; 1.0551x over previous
//
#include <hip/hip_runtime.h>
#include <stdint.h>

#define S_LEN 2048
#define DMODEL 1024
#define NHEAD 16
#define DKH 64
#define NROW 4096  // B*S

using short8  = __attribute__((ext_vector_type(8))) short;
using short4v = __attribute__((ext_vector_type(4))) short;
using float4v = __attribute__((ext_vector_type(4))) float;

__device__ __forceinline__ short f2bf(float f) {
    union { float f; unsigned u; } v; v.f = f;
    unsigned r = (v.u + 0x7fffu + ((v.u >> 16) & 1u)) >> 16;
    return (short)r;
}

__device__ __forceinline__ float bf2f(short b) {
    union { unsigned u; float f; } c;
    c.u = ((unsigned)(unsigned short)b) << 16;
    return c.f;
}

__device__ __forceinline__ float4v mfma16(short8 a, short8 b, float4v c) {
    return __builtin_amdgcn_mfma_f32_16x16x32_bf16(a, b, c, 0, 0, 0);
}

// async global->LDS, 16B per lane. LDS dest = wave-uniform base + lane*16.
__device__ __forceinline__ void gload16(const short* g, short* l) {
    __builtin_amdgcn_global_load_lds(
        (const __attribute__((address_space(1))) void*)g,
        (__attribute__((address_space(3))) void*)l, 16, 0, 0);
}

// ---------------------------------------------------------------- convert
__global__ __launch_bounds__(256) void convert_kernel(
    const float* __restrict__ q, const float* __restrict__ k, const float* __restrict__ v,
    const float* __restrict__ wq, const float* __restrict__ wk, const float* __restrict__ wv,
    const float* __restrict__ wo,
    short* __restrict__ oq, short* __restrict__ ok_, short* __restrict__ ov,
    short* __restrict__ owq, short* __restrict__ owk, short* __restrict__ owv,
    short* __restrict__ owo)
{
    const size_t A = (size_t)NROW * DMODEL;      // 4194304
    const size_t W = (size_t)DMODEL * DMODEL;    // 1048576
    size_t i = ((size_t)blockIdx.x * 256 + threadIdx.x) * 4;
    const float* src; short* dst; size_t off;
    if (i < A)            { src = q;  dst = oq;  off = i; }
    else if (i < 2 * A)   { src = k;  dst = ok_; off = i - A; }
    else if (i < 3 * A)   { src = v;  dst = ov;  off = i - 2 * A; }
    else {
        size_t j = i - 3 * A; int wsel = (int)(j / W); off = j % W;
        src = (wsel == 0) ? wq : (wsel == 1) ? wk : (wsel == 2) ? wv : wo;
        dst = (wsel == 0) ? owq : (wsel == 1) ? owk : (wsel == 2) ? owv : owo;
    }
    float4v x = *(const float4v*)(src + off);
    short4v o;
    o[0] = f2bf(x[0]); o[1] = f2bf(x[1]); o[2] = f2bf(x[2]); o[3] = f2bf(x[3]);
    *(short4v*)(dst + off) = o;
}

// ---------------------------------------------------------------- fused QKV GEMM (m97 structure)
__global__ __launch_bounds__(256) void gemm_qkv(
    const short* __restrict__ Xq, const short* __restrict__ Xk, const short* __restrict__ Xv,
    const short* __restrict__ Wq, const short* __restrict__ Wk, const short* __restrict__ Wv,
    const float* __restrict__ bq, const float* __restrict__ bk, const float* __restrict__ bv,
    short* __restrict__ Qo, short* __restrict__ Ko, short* __restrict__ Vt)
{
    int zy = blockIdx.y;
    int z = zy >> 3;                 // 0=Q 1=K 2=V
    int n0 = (zy & 7) * 128;
    const short* X = (z == 0) ? Xq : (z == 1) ? Xk : Xv;
    const short* W = (z == 0) ? Wq : (z == 1) ? Wk : Wv;
    const float* bias = (z == 0) ? bq : (z == 1) ? bk : bv;
    int m0 = blockIdx.x * 128;

    __shared__ __align__(16) short As[128 * 32];
    __shared__ __align__(16) short Bs[128 * 32];

    int tid = threadIdx.x, lane = tid & 63, w = tid >> 6;
    int row_in = lane & 15, grp = lane >> 4;
    int wm = (w & 1) * 64, wn = (w >> 1) * 64;

    float4v acc[4][4];
#pragma unroll
    for (int m = 0; m < 4; m++)
#pragma unroll
        for (int n = 0; n < 4; n++) acc[m][n] = (float4v){0.f, 0.f, 0.f, 0.f};

    for (int k0 = 0; k0 < DMODEL; k0 += 32) {
#pragma unroll
        for (int j = 0; j < 2; j++) {
            int chunk = j * 256 + tid;
            int r = chunk >> 2, c = (chunk & 3) * 8;
            gload16(X + (size_t)(m0 + r) * DMODEL + k0 + c,
                    As + (size_t)(j * 256 + w * 64) * 8);
            gload16(W + (size_t)(n0 + r) * DMODEL + k0 + c,
                    Bs + (size_t)(j * 256 + w * 64) * 8);
        }
        __syncthreads();

        short8 af[4], bf[4];
#pragma unroll
        for (int m = 0; m < 4; m++)
            af[m] = *(const short8*)&As[(wm + m * 16 + row_in) * 32 + grp * 8];
#pragma unroll
        for (int n = 0; n < 4; n++)
            bf[n] = *(const short8*)&Bs[(wn + n * 16 + row_in) * 32 + grp * 8];
#pragma unroll
        for (int m = 0; m < 4; m++)
#pragma unroll
            for (int n = 0; n < 4; n++)
                acc[m][n] = mfma16(af[m], bf[n], acc[m][n]);
        __syncthreads();
    }

#pragma unroll
    for (int m = 0; m < 4; m++) {
#pragma unroll
        for (int n = 0; n < 4; n++) {
            int col = n0 + wn + n * 16 + row_in;
            int h = col >> 6, dk = col & 63;
            float bval = bias[col];
            if (z < 2) {
                short* dst = (z == 0) ? Qo : Ko;
#pragma unroll
                for (int r = 0; r < 4; r++) {
                    int rowg = m0 + wm + m * 16 + grp * 4 + r;
                    int bb = rowg >> 11, s = rowg & 2047;
                    dst[(((size_t)(bb * NHEAD + h)) * S_LEN + s) * DKH + dk] =
                        f2bf(acc[m][n][r] + bval);
                }
            } else {
                int rowg0 = m0 + wm + m * 16 + grp * 4;
                int bb = rowg0 >> 11, s0 = rowg0 & 2047;
                short4v pk;
#pragma unroll
                for (int r = 0; r < 4; r++) pk[r] = f2bf(acc[m][n][r] + bval);
                *(short4v*)(Vt + ((size_t)(bb * NHEAD + h) * DKH + dk) * S_LEN + s0) = pk;
            }
        }
    }
}

// ---------------------------------------------------------------- output projection
__global__ __launch_bounds__(256) void gemm_out(
    const short* __restrict__ X, const short* __restrict__ W,
    const float* __restrict__ bias, float* __restrict__ out)
{
    int m0 = blockIdx.x * 128, n0 = blockIdx.y * 128;

    __shared__ __align__(16) short As[128 * 32];
    __shared__ __align__(16) short Bs[128 * 32];

    int tid = threadIdx.x, lane = tid & 63, w = tid >> 6;
    int row_in = lane & 15, grp = lane >> 4;
    int wm = (w & 1) * 64, wn = (w >> 1) * 64;

    float4v acc[4][4];
#pragma unroll
    for (int m = 0; m < 4; m++)
#pragma unroll
        for (int n = 0; n < 4; n++) acc[m][n] = (float4v){0.f, 0.f, 0.f, 0.f};

    for (int k0 = 0; k0 < DMODEL; k0 += 32) {
#pragma unroll
        for (int j = 0; j < 2; j++) {
            int chunk = j * 256 + tid;
            int r = chunk >> 2, c = (chunk & 3) * 8;
            gload16(X + (size_t)(m0 + r) * DMODEL + k0 + c,
                    As + (size_t)(j * 256 + w * 64) * 8);
            gload16(W + (size_t)(n0 + r) * DMODEL + k0 + c,
                    Bs + (size_t)(j * 256 + w * 64) * 8);
        }
        __syncthreads();

        short8 af[4], bf[4];
#pragma unroll
        for (int m = 0; m < 4; m++)
            af[m] = *(const short8*)&As[(wm + m * 16 + row_in) * 32 + grp * 8];
#pragma unroll
        for (int n = 0; n < 4; n++)
            bf[n] = *(const short8*)&Bs[(wn + n * 16 + row_in) * 32 + grp * 8];
#pragma unroll
        for (int m = 0; m < 4; m++)
#pragma unroll
            for (int n = 0; n < 4; n++)
                acc[m][n] = mfma16(af[m], bf[n], acc[m][n]);
        __syncthreads();
    }

#pragma unroll
    for (int m = 0; m < 4; m++)
#pragma unroll
        for (int n = 0; n < 4; n++) {
            int col = n0 + wn + n * 16 + row_in;
            float bval = bias[col];
#pragma unroll
            for (int r = 0; r < 4; r++) {
                int rowg = m0 + wm + m * 16 + grp * 4 + r;
                out[(size_t)rowg * DMODEL + col] = acc[m][n][r] + bval;
            }
        }
}

// ---------------------------------------------------------------- fused attention
// EXACT 731-baseline structure; ONLY change: K/V staging uses async
// global_load_lds (no VGPR round-trip / ds_writes). Padding is replaced by the
// rule-#21 both-sides XOR swizzle: linear [64][64] LDS, global source column
// group cg^(r&7), ds_read column group cg^(R&7). Data read is identical;
// banks spread 8-ways per 16-lane group (2-way residual = free).
__global__ __launch_bounds__(256) void attn_kernel(
    const short* __restrict__ Q, const short* __restrict__ K, const short* __restrict__ Vt,
    float* __restrict__ Attn, short* __restrict__ Xatt)
{
    int bh = blockIdx.x;
    int q0 = blockIdx.y * 64;
    int tid = threadIdx.x, lane = tid & 63, w = tid >> 6;
    int row_in = lane & 15, grp = lane >> 4;
    int qbase = q0 + w * 16;

    const short* Qh = Q + (size_t)bh * S_LEN * DKH;
    const short* Kh = K + (size_t)bh * S_LEN * DKH;
    const short* Vh = Vt + (size_t)bh * DKH * S_LEN;
    float* Ah = Attn + (size_t)bh * S_LEN * S_LEN;

    __shared__ __align__(16) short Ks[64 * 64];      // 8192 B, linear (gload_lds dest)
    __shared__ __align__(16) short Vs[64 * 64];      // 8192 B, linear
    __shared__ __align__(16) short Plds[4][16 * 72]; // 9216 B (wave-private, reg-staged)

    short8 qf0 = *(const short8*)(Qh + (size_t)(qbase + row_in) * DKH + grp * 8);
    short8 qf1 = *(const short8*)(Qh + (size_t)(qbase + row_in) * DKH + 32 + grp * 8);

    const float SC = 0.125f * 1.44269504f;  // fold score scale into exp2
    float l[4] = {0.f, 0.f, 0.f, 0.f};
    int Tmax = q0 / 64 + 1;  // causal tiles for this block

    // ---- pass 1: softmax denominators (no max subtraction needed)
    for (int t = 0; t < Tmax; t++) {
        int kv0 = t * 64;
        // async K-tile stage: chunk (r, cg) <- global (r, cg^(r&7)); LDS linear
        {
#pragma unroll
            for (int j = 0; j < 2; j++) {
                int ch = j * 256 + tid;
                int r = ch >> 3, cg = ch & 7;
                gload16(Kh + (size_t)(kv0 + r) * DKH + ((cg ^ (r & 7)) * 8),
                        Ks + (size_t)(j * 256 + w * 64) * 8);
            }
        }
        __syncthreads();
#pragma unroll
        for (int u = 0; u < 4; u++) {
            int R = u * 16 + row_in;
            short8 b0 = *(const short8*)&Ks[R * 64 + ((grp ^ (R & 7)) * 8)];
            short8 b1 = *(const short8*)&Ks[R * 64 + (((grp + 4) ^ (R & 7)) * 8)];
            float4v a = (float4v){0.f, 0.f, 0.f, 0.f};
            a = mfma16(qf0, b0, a);
            a = mfma16(qf1, b1, a);
            int colg = kv0 + R;
#pragma unroll
            for (int r = 0; r < 4; r++) {
                int rowg = qbase + grp * 4 + r;
                float e = (colg > rowg) ? 0.0f : exp2f(a[r] * SC);
                l[r] += e;
            }
        }
        __syncthreads();
    }
    // cross-lane row sums (16 column-lanes per row group)
    float rinv[4];
#pragma unroll
    for (int r = 0; r < 4; r++) {
        float s = l[r];
        s += __shfl_xor(s, 1, 64);
        s += __shfl_xor(s, 2, 64);
        s += __shfl_xor(s, 4, 64);
        s += __shfl_xor(s, 8, 64);
        rinv[r] = 1.0f / s;
    }

    float4v o[4];
#pragma unroll
    for (int v = 0; v < 4; v++) o[v] = (float4v){0.f, 0.f, 0.f, 0.f};

    // ---- pass 2: recompute + write normalized attention + PV
    for (int t = 0; t < Tmax; t++) {
        int kv0 = t * 64;
        {
#pragma unroll
            for (int j = 0; j < 2; j++) {
                int ch = j * 256 + tid;
                int r = ch >> 3, cg = ch & 7;
                gload16(Kh + (size_t)(kv0 + r) * DKH + ((cg ^ (r & 7)) * 8),
                        Ks + (size_t)(j * 256 + w * 64) * 8);
                gload16(Vh + (size_t)r * S_LEN + kv0 + ((cg ^ (r & 7)) * 8),
                        Vs + (size_t)(j * 256 + w * 64) * 8);
            }
        }
        __syncthreads();
#pragma unroll
        for (int u = 0; u < 4; u++) {
            int R = u * 16 + row_in;
            short8 b0 = *(const short8*)&Ks[R * 64 + ((grp ^ (R & 7)) * 8)];
            short8 b1 = *(const short8*)&Ks[R * 64 + (((grp + 4) ^ (R & 7)) * 8)];
            float4v a = (float4v){0.f, 0.f, 0.f, 0.f};
            a = mfma16(qf0, b0, a);
            a = mfma16(qf1, b1, a);
            int colg = kv0 + R;
#pragma unroll
            for (int r = 0; r < 4; r++) {
                int rowg = qbase + grp * 4 + r;
                float p = (colg > rowg) ? 0.0f : exp2f(a[r] * SC) * rinv[r];
                Plds[w][(grp * 4 + r) * 72 + u * 16 + row_in] = f2bf(p);
            }
        }
        asm volatile("s_waitcnt lgkmcnt(0)" ::: "memory");
        // coalesced f32 attention write from bf16 P (error <= 2^-9, well under threshold)
#pragma unroll
        for (int rr = 0; rr < 4; rr++) {
            int rloc = rr * 4 + grp;
            short4v pb = *(const short4v*)&Plds[w][rloc * 72 + row_in * 4];
            float4v pf;
#pragma unroll
            for (int i = 0; i < 4; i++) pf[i] = bf2f(pb[i]);
            *(float4v*)(Ah + (size_t)(qbase + rloc) * S_LEN + kv0 + row_in * 4) = pf;
        }
        short8 pa0 = *(const short8*)&Plds[w][row_in * 72 + grp * 8];
        short8 pa1 = *(const short8*)&Plds[w][row_in * 72 + 32 + grp * 8];
#pragma unroll
        for (int v = 0; v < 4; v++) {
            int R = v * 16 + row_in;
            short8 b0 = *(const short8*)&Vs[R * 64 + ((grp ^ (R & 7)) * 8)];
            short8 b1 = *(const short8*)&Vs[R * 64 + (((grp + 4) ^ (R & 7)) * 8)];
            o[v] = mfma16(pa0, b0, o[v]);
            o[v] = mfma16(pa1, b1, o[v]);
        }
        __syncthreads();
    }

    // ---- zero fill above the causal range (no barriers needed)
    float4v zz = (float4v){0.f, 0.f, 0.f, 0.f};
    for (int kv0 = Tmax * 64; kv0 < S_LEN; kv0 += 64) {
#pragma unroll
        for (int r = 0; r < 4; r++) {
            int rowg = qbase + r * 4 + grp;
            *(float4v*)(Ah + (size_t)rowg * S_LEN + kv0 + row_in * 4) = zz;
        }
    }

    // ---- epilogue: O -> Xatt (bf16, [B,S,D] with col = h*64+dk)
    int b = bh >> 4, h = bh & 15;
#pragma unroll
    for (int v = 0; v < 4; v++) {
#pragma unroll
        for (int r = 0; r < 4; r++) {
            int s = qbase + grp * 4 + r;
            int col = h * 64 + v * 16 + row_in;
            Xatt[(size_t)(b * S_LEN + s) * DMODEL + col] = f2bf(o[v][r]);
        }
    }
}

// ---------------------------------------------------------------- launch
extern "C" void kernel_launch(void* const* d_in, const int* in_sizes, int n_in,
                              void* d_out, int out_size, void* d_ws, size_t ws_size,
                              hipStream_t stream) {
    const float* q  = (const float*)d_in[0];
    const float* k  = (const float*)d_in[1];
    const float* v  = (const float*)d_in[2];
    const float* Wq = (const float*)d_in[4];
    const float* bq = (const float*)d_in[5];
    const float* Wk = (const float*)d_in[6];
    const float* bk = (const float*)d_in[7];
    const float* Wv = (const float*)d_in[8];
    const float* bv = (const float*)d_in[9];
    const float* Wo = (const float*)d_in[10];
    const float* bo = (const float*)d_in[11];

    float* out_x    = (float*)d_out;
    float* out_attn = out_x + (size_t)NROW * DMODEL;

    char* ws = (char*)d_ws;
    size_t off = 0;
    auto carve = [&](size_t bytes) -> char* {
        char* p = ws + off;
        off += (bytes + 255) & ~(size_t)255;
        return p;
    };
    const size_t XB = (size_t)NROW * DMODEL * sizeof(short);
    const size_t WB = (size_t)DMODEL * DMODEL * sizeof(short);
    short* Xq  = (short*)carve(XB);
    short* Xk  = (short*)carve(XB);
    short* Xv  = (short*)carve(XB);
    short* Wqb = (short*)carve(WB);
    short* Wkb = (short*)carve(WB);
    short* Wvb = (short*)carve(WB);
    short* Wob = (short*)carve(WB);
    short* Qb  = (short*)carve(XB);   // [BH, S, DK]
    short* Kb  = (short*)carve(XB);   // [BH, S, DK]
    short* Vtb = (short*)carve(XB);   // [BH, DK, S]
    short* Xat = (short*)carve(XB);   // attention output pre-Wo

    convert_kernel<<<dim3(16384), dim3(256), 0, stream>>>(
        q, k, v, Wq, Wk, Wv, Wo, Xq, Xk, Xv, Wqb, Wkb, Wvb, Wob);

    gemm_qkv<<<dim3(NROW / 128, 24), dim3(256), 0, stream>>>(
        Xq, Xk, Xv, Wqb, Wkb, Wvb, bq, bk, bv, Qb, Kb, Vtb);

    attn_kernel<<<dim3(32, S_LEN / 64), dim3(256), 0, stream>>>(
        Qb, Kb, Vtb, out_attn, Xat);

    gemm_out<<<dim3(NROW / 128, DMODEL / 128), dim3(256), 0, stream>>>(
        Xat, Wob, bo, out_x);
}